// Round 2
// 631.413 us; speedup vs baseline: 1.0011x; 1.0011x over previous
//
#include <hip/hip_runtime.h>
#include <cstddef>
#include <cstdint>

// HyenaCascade: depthwise causal conv (K=3) -> 8-pole diagonal SSM scan
// (exact replacement for the reference's FFT long-conv) -> gated output.
//
// v3: same latency-bound diagnosis as v2, vanilla-HIP fix (v2's container
// failed; removing global_load_lds/LDS/barriers to de-risk):
//  - 2 adjacent channels per thread -> every operand load is a float2 (8 B),
//    a wave covers one head -> 512 B contiguous segments, fully coalesced.
//  - rows processed in double-buffered batches of 4 (named bufA/bufB, all
//    statically indexed) -> 8-12 independent loads in flight per wave while
//    the previous batch's conv+scan math runs.
namespace {
constexpr int kB   = 2;
constexpr int kL   = 8192;
constexpr int kHid = 2048;   // HIDDEN == GROUPS
constexpr int kC3  = 6144;   // 3*HIDDEN
constexpr int kS   = 8;      // state size
constexpr int kNC  = 64;     // sequence chunks
constexpr int kCL  = kL / kNC;   // 128 rows per chunk
constexpr int kRB  = 4;          // rows per load batch
constexpr int kNB  = kCL / kRB;  // 32 batches (even, needed for A/B unroll)
} // namespace

// ---------------------------------------------------------------------------
// Pass 1: per (b, chunk, channel-pair) compute x1v = x1*v via the K=3
// depthwise conv, scan from zero state, store chunk-end state A[b][c][d][s].
// Block = 256 threads = 4 heads; thread owns channels d0, d0+1.
// ---------------------------------------------------------------------------
__global__ __launch_bounds__(256) void hyena_pass1(
    const float* __restrict__ u, const float* __restrict__ w,
    const float* __restrict__ bias, const float* __restrict__ lp,
    float* __restrict__ A)
{
  const int tid  = threadIdx.x;
  const int ch   = blockIdx.y;
  const int b    = blockIdx.z;
  const int head = blockIdx.x * 4 + (tid >> 6);   // wave == one head
  const int r2   = (tid & 63) * 2;
  const int d0   = head * 128 + r2;               // first of channel pair
  const int c1   = head * 384 + 128 + r2;         // x1 channel in u
  const int cv   = c1 + 128;                      // v channel

  float w1k[2][3], wvk[2][3], b1[2], bv[2];
  #pragma unroll
  for (int q = 0; q < 2; ++q) {
    #pragma unroll
    for (int k = 0; k < 3; ++k) {
      w1k[q][k] = w[(c1 + q) * 3 + k];
      wvk[q][k] = w[(cv + q) * 3 + k];
    }
    b1[q] = bias[c1 + q];
    bv[q] = bias[cv + q];
  }

  float p[2][kS], s[2][kS];
  #pragma unroll
  for (int q = 0; q < 2; ++q)
    #pragma unroll
    for (int j = 0; j < kS; ++j) {
      p[q][j] = expf(lp[(d0 + q) * kS + j]);
      s[q][j] = 0.f;
    }

  const int l0 = ch * kCL;
  const float* ub = u + (size_t)b * kL * kC3;

  float m2_1[2] = {0.f, 0.f}, m1_1[2] = {0.f, 0.f};
  float m2_v[2] = {0.f, 0.f}, m1_v[2] = {0.f, 0.f};
  if (l0 >= 2) {
    float2 t1 = *(const float2*)&ub[(size_t)(l0 - 2) * kC3 + c1];
    float2 tv = *(const float2*)&ub[(size_t)(l0 - 2) * kC3 + cv];
    m2_1[0] = t1.x; m2_1[1] = t1.y; m2_v[0] = tv.x; m2_v[1] = tv.y;
  }
  if (l0 >= 1) {
    float2 t1 = *(const float2*)&ub[(size_t)(l0 - 1) * kC3 + c1];
    float2 tv = *(const float2*)&ub[(size_t)(l0 - 1) * kC3 + cv];
    m1_1[0] = t1.x; m1_1[1] = t1.y; m1_v[0] = tv.x; m1_v[1] = tv.y;
  }

  const float* up = ub + (size_t)l0 * kC3;

  float2 a1A[kRB], avA[kRB], a1B[kRB], avB[kRB];

  auto loadb = [&](float2 (&a1)[kRB], float2 (&av)[kRB], int t) {
    const float* rp = up + (size_t)t * kRB * kC3;
    #pragma unroll
    for (int k = 0; k < kRB; ++k) {
      a1[k] = *(const float2*)&rp[(size_t)k * kC3 + c1];
      av[k] = *(const float2*)&rp[(size_t)k * kC3 + cv];
    }
  };

  auto comp = [&](const float2 (&a1)[kRB], const float2 (&av)[kRB]) {
    #pragma unroll
    for (int k = 0; k < kRB; ++k) {
      const float c1v[2] = {a1[k].x, a1[k].y};
      const float cvv[2] = {av[k].x, av[k].y};
      #pragma unroll
      for (int q = 0; q < 2; ++q) {
        const float x1 = fmaf(w1k[q][0], m2_1[q],
                         fmaf(w1k[q][1], m1_1[q],
                         fmaf(w1k[q][2], c1v[q], b1[q])));
        const float v  = fmaf(wvk[q][0], m2_v[q],
                         fmaf(wvk[q][1], m1_v[q],
                         fmaf(wvk[q][2], cvv[q], bv[q])));
        const float x = x1 * v;
        #pragma unroll
        for (int j = 0; j < kS; ++j) s[q][j] = fmaf(p[q][j], s[q][j], x);
        m2_1[q] = m1_1[q]; m1_1[q] = c1v[q];
        m2_v[q] = m1_v[q]; m1_v[q] = cvv[q];
      }
    }
  };

  loadb(a1A, avA, 0);
  for (int t = 0; t < kNB; t += 2) {
    if (t + 1 < kNB) loadb(a1B, avB, t + 1);
    comp(a1A, avA);
    if (t + 2 < kNB) loadb(a1A, avA, t + 2);
    comp(a1B, avB);
  }

  float* Ad = A + (((size_t)b * kNC + ch) * kHid + d0) * kS;
  #pragma unroll
  for (int q = 0; q < 2; ++q)
    #pragma unroll
    for (int j = 0; j < kS; ++j) Ad[q * kS + j] = s[q][j];
}

// ---------------------------------------------------------------------------
// Pass 2: in-place inclusive combine across chunks:
//   S[c] = p^CL * S[c-1] + A[c]   (per (b,d,s) line; lines are disjoint)
// ---------------------------------------------------------------------------
__global__ __launch_bounds__(256) void hyena_pass2(
    const float* __restrict__ lp, float* __restrict__ A)
{
  const int t = blockIdx.x * 256 + threadIdx.x;    // over B*HID*S = 32768
  const int j = t & (kS - 1);
  const int d = (t >> 3) & (kHid - 1);
  const int b = t >> 14;
  const float pC = expf(lp[d*kS + j] * (float)kCL);

  const size_t base   = (size_t)b * kNC * kHid * kS + (size_t)d * kS + j;
  const size_t stride = (size_t)kHid * kS;

  float s = 0.f;
  for (int c0 = 0; c0 < kNC; c0 += 8) {
    float a[8];
    #pragma unroll
    for (int k = 0; k < 8; ++k) a[k] = A[base + (size_t)(c0 + k) * stride];
    #pragma unroll
    for (int k = 0; k < 8; ++k) {
      s = fmaf(pC, s, a[k]);
      A[base + (size_t)(c0 + k) * stride] = s;
    }
  }
}

// ---------------------------------------------------------------------------
// Pass 3: re-derive x2/x1/v from u, scan with the combined incoming state
// (end-state of chunk-1), emit out[b][l][d] = (y + x1v*D) * x2.
// Same thread mapping as pass 1; float2 loads for all three operands,
// float2 stores for the output pair.
// ---------------------------------------------------------------------------
__global__ __launch_bounds__(256) void hyena_pass3(
    const float* __restrict__ u, const float* __restrict__ w,
    const float* __restrict__ bias, const float* __restrict__ lp,
    const float* __restrict__ res, const float* __restrict__ Dv,
    const float* __restrict__ A, float* __restrict__ out)
{
  const int tid  = threadIdx.x;
  const int ch   = blockIdx.y;
  const int b    = blockIdx.z;
  const int head = blockIdx.x * 4 + (tid >> 6);
  const int r2   = (tid & 63) * 2;
  const int d0   = head * 128 + r2;
  const int c2   = head * 384 + r2;       // x2 channel
  const int c1   = c2 + 128;              // x1 channel
  const int cv   = c2 + 256;              // v channel

  float w2k[2][3], w1k[2][3], wvk[2][3], b2[2], b1[2], bv[2], Dd[2];
  #pragma unroll
  for (int q = 0; q < 2; ++q) {
    #pragma unroll
    for (int k = 0; k < 3; ++k) {
      w2k[q][k] = w[(c2 + q) * 3 + k];
      w1k[q][k] = w[(c1 + q) * 3 + k];
      wvk[q][k] = w[(cv + q) * 3 + k];
    }
    b2[q] = bias[c2 + q];
    b1[q] = bias[c1 + q];
    bv[q] = bias[cv + q];
    Dd[q] = Dv[d0 + q];
  }

  float p[2][kS], rr[2][kS], s[2][kS];
  #pragma unroll
  for (int q = 0; q < 2; ++q)
    #pragma unroll
    for (int j = 0; j < kS; ++j) {
      p[q][j]  = expf(lp[(d0 + q) * kS + j]);
      rr[q][j] = res[(d0 + q) * kS + j];
    }
  if (ch == 0) {
    #pragma unroll
    for (int q = 0; q < 2; ++q)
      #pragma unroll
      for (int j = 0; j < kS; ++j) s[q][j] = 0.f;
  } else {
    const float* Ad = A + (((size_t)b * kNC + (ch - 1)) * kHid + d0) * kS;
    #pragma unroll
    for (int q = 0; q < 2; ++q)
      #pragma unroll
      for (int j = 0; j < kS; ++j) s[q][j] = Ad[q * kS + j];
  }

  const int l0 = ch * kCL;
  const float* ub = u + (size_t)b * kL * kC3;

  float m2_2[2] = {0.f, 0.f}, m1_2[2] = {0.f, 0.f};
  float m2_1[2] = {0.f, 0.f}, m1_1[2] = {0.f, 0.f};
  float m2_v[2] = {0.f, 0.f}, m1_v[2] = {0.f, 0.f};
  if (l0 >= 2) {
    float2 t2 = *(const float2*)&ub[(size_t)(l0 - 2) * kC3 + c2];
    float2 t1 = *(const float2*)&ub[(size_t)(l0 - 2) * kC3 + c1];
    float2 tv = *(const float2*)&ub[(size_t)(l0 - 2) * kC3 + cv];
    m2_2[0] = t2.x; m2_2[1] = t2.y;
    m2_1[0] = t1.x; m2_1[1] = t1.y;
    m2_v[0] = tv.x; m2_v[1] = tv.y;
  }
  if (l0 >= 1) {
    float2 t2 = *(const float2*)&ub[(size_t)(l0 - 1) * kC3 + c2];
    float2 t1 = *(const float2*)&ub[(size_t)(l0 - 1) * kC3 + c1];
    float2 tv = *(const float2*)&ub[(size_t)(l0 - 1) * kC3 + cv];
    m1_2[0] = t2.x; m1_2[1] = t2.y;
    m1_1[0] = t1.x; m1_1[1] = t1.y;
    m1_v[0] = tv.x; m1_v[1] = tv.y;
  }

  const float* up = ub + (size_t)l0 * kC3;
  float* ob = out + ((size_t)b * kL + l0) * kHid + d0;

  float2 a2A[kRB], a1A[kRB], avA[kRB];
  float2 a2B[kRB], a1B[kRB], avB[kRB];

  auto loadb = [&](float2 (&a2)[kRB], float2 (&a1)[kRB], float2 (&av)[kRB],
                   int t) {
    const float* rp = up + (size_t)t * kRB * kC3;
    #pragma unroll
    for (int k = 0; k < kRB; ++k) {
      a2[k] = *(const float2*)&rp[(size_t)k * kC3 + c2];
      a1[k] = *(const float2*)&rp[(size_t)k * kC3 + c1];
      av[k] = *(const float2*)&rp[(size_t)k * kC3 + cv];
    }
  };

  auto comp = [&](const float2 (&a2)[kRB], const float2 (&a1)[kRB],
                  const float2 (&av)[kRB], int t) {
    #pragma unroll
    for (int k = 0; k < kRB; ++k) {
      const float c2v[2] = {a2[k].x, a2[k].y};
      const float c1v[2] = {a1[k].x, a1[k].y};
      const float cvv[2] = {av[k].x, av[k].y};
      float o[2];
      #pragma unroll
      for (int q = 0; q < 2; ++q) {
        const float x2 = fmaf(w2k[q][0], m2_2[q],
                         fmaf(w2k[q][1], m1_2[q],
                         fmaf(w2k[q][2], c2v[q], b2[q])));
        const float x1 = fmaf(w1k[q][0], m2_1[q],
                         fmaf(w1k[q][1], m1_1[q],
                         fmaf(w1k[q][2], c1v[q], b1[q])));
        const float v  = fmaf(wvk[q][0], m2_v[q],
                         fmaf(wvk[q][1], m1_v[q],
                         fmaf(wvk[q][2], cvv[q], bv[q])));
        const float x = x1 * v;
        #pragma unroll
        for (int j = 0; j < kS; ++j) s[q][j] = fmaf(p[q][j], s[q][j], x);
        float y = 0.f;
        #pragma unroll
        for (int j = 0; j < kS; ++j) y = fmaf(rr[q][j], s[q][j], y);
        o[q] = fmaf(x, Dd[q], y) * x2;
        m2_2[q] = m1_2[q]; m1_2[q] = c2v[q];
        m2_1[q] = m1_1[q]; m1_1[q] = c1v[q];
        m2_v[q] = m1_v[q]; m1_v[q] = cvv[q];
      }
      *(float2*)&ob[(size_t)(t * kRB + k) * kHid] = make_float2(o[0], o[1]);
    }
  };

  loadb(a2A, a1A, avA, 0);
  for (int t = 0; t < kNB; t += 2) {
    if (t + 1 < kNB) loadb(a2B, a1B, avB, t + 1);
    comp(a2A, a1A, avA, t);
    if (t + 2 < kNB) loadb(a2A, a1A, avA, t + 2);
    comp(a2B, a1B, avB, t + 1);
  }
}

extern "C" void kernel_launch(void* const* d_in, const int* in_sizes, int n_in,
                              void* d_out, int out_size, void* d_ws, size_t ws_size,
                              hipStream_t stream) {
  const float* u    = (const float*)d_in[0];  // [B, L, 3*HID] fp32
  const float* w    = (const float*)d_in[1];  // [3*HID, 1, 3]
  const float* bias = (const float*)d_in[2];  // [3*HID]
  const float* lp   = (const float*)d_in[3];  // [HID, S, 1]
  const float* res  = (const float*)d_in[4];  // [HID, S]
  const float* Dv   = (const float*)d_in[5];  // [HID]
  float* out = (float*)d_out;                 // [B, L, HID]
  float* A   = (float*)d_ws;                  // [B, NC, HID, S] = 8 MB

  const dim3 blk(256);
  const dim3 g13(kHid / 512, kNC, kB);        // (head-quads, chunks, batch)
  hipLaunchKernelGGL(hyena_pass1, g13, blk, 0, stream, u, w, bias, lp, A);
  hipLaunchKernelGGL(hyena_pass2, dim3((kB * kHid * kS) / 256), blk, 0, stream, lp, A);
  hipLaunchKernelGGL(hyena_pass3, g13, blk, 0, stream, u, w, bias, lp, res, Dv, A, out);
}

// Round 3
// 602.023 us; speedup vs baseline: 1.0499x; 1.0488x over previous
//
#include <hip/hip_runtime.h>
#include <hip/hip_fp16.h>
#include <cstddef>
#include <cstdint>

// HyenaCascade: depthwise causal conv (K=3) -> 8-pole diagonal SSM scan
// (exact replacement for the reference's FFT long-conv) -> gated output.
//
// v4: timing decomposition shows ~494 us of the 632 us is harness workspace
// poison (2 x 1.6 GB fills @ ~247 us); our kernels are ~138 us ~= the
// compulsory-traffic roofline for the v3 dataflow (~830 MB @ 6.3 TB/s).
// Remaining lever is algorithmic traffic: pass1 now stores x1v as fp16
// (67 MB round-trip) so pass3 no longer re-reads the x1/v columns of u
// (268 MB fp32). Net -134 MB => kernels ~114 us.
namespace {
constexpr int kB   = 2;
constexpr int kL   = 8192;
constexpr int kHid = 2048;   // HIDDEN == GROUPS
constexpr int kC3  = 6144;   // 3*HIDDEN
constexpr int kS   = 8;      // state size
constexpr int kNC  = 64;     // sequence chunks
constexpr int kCL  = kL / kNC;   // 128 rows per chunk
constexpr int kRB  = 4;          // rows per load batch
constexpr int kNB  = kCL / kRB;  // 32 batches (even, needed for A/B unroll)
} // namespace

// ---------------------------------------------------------------------------
// Pass 1: per (b, chunk, channel-pair) compute x1v = x1*v via the K=3
// depthwise conv, scan from zero state, store chunk-end state A[b][c][d][s],
// and store x1v as fp16 to xw[b][l][d] for pass 3.
// Block = 256 threads = 4 heads; thread owns channels d0, d0+1.
// ---------------------------------------------------------------------------
__global__ __launch_bounds__(256) void hyena_pass1(
    const float* __restrict__ u, const float* __restrict__ w,
    const float* __restrict__ bias, const float* __restrict__ lp,
    float* __restrict__ A, __half* __restrict__ xw)
{
  const int tid  = threadIdx.x;
  const int ch   = blockIdx.y;
  const int b    = blockIdx.z;
  const int head = blockIdx.x * 4 + (tid >> 6);   // wave == one head
  const int r2   = (tid & 63) * 2;
  const int d0   = head * 128 + r2;               // first of channel pair
  const int c1   = head * 384 + 128 + r2;         // x1 channel in u
  const int cv   = c1 + 128;                      // v channel

  float w1k[2][3], wvk[2][3], b1[2], bv[2];
  #pragma unroll
  for (int q = 0; q < 2; ++q) {
    #pragma unroll
    for (int k = 0; k < 3; ++k) {
      w1k[q][k] = w[(c1 + q) * 3 + k];
      wvk[q][k] = w[(cv + q) * 3 + k];
    }
    b1[q] = bias[c1 + q];
    bv[q] = bias[cv + q];
  }

  float p[2][kS], s[2][kS];
  #pragma unroll
  for (int q = 0; q < 2; ++q)
    #pragma unroll
    for (int j = 0; j < kS; ++j) {
      p[q][j] = expf(lp[(d0 + q) * kS + j]);
      s[q][j] = 0.f;
    }

  const int l0 = ch * kCL;
  const float* ub = u + (size_t)b * kL * kC3;

  float m2_1[2] = {0.f, 0.f}, m1_1[2] = {0.f, 0.f};
  float m2_v[2] = {0.f, 0.f}, m1_v[2] = {0.f, 0.f};
  if (l0 >= 2) {
    float2 t1 = *(const float2*)&ub[(size_t)(l0 - 2) * kC3 + c1];
    float2 tv = *(const float2*)&ub[(size_t)(l0 - 2) * kC3 + cv];
    m2_1[0] = t1.x; m2_1[1] = t1.y; m2_v[0] = tv.x; m2_v[1] = tv.y;
  }
  if (l0 >= 1) {
    float2 t1 = *(const float2*)&ub[(size_t)(l0 - 1) * kC3 + c1];
    float2 tv = *(const float2*)&ub[(size_t)(l0 - 1) * kC3 + cv];
    m1_1[0] = t1.x; m1_1[1] = t1.y; m1_v[0] = tv.x; m1_v[1] = tv.y;
  }

  const float* up = ub + (size_t)l0 * kC3;
  __half* xb = xw + ((size_t)b * kL + l0) * kHid + d0;

  float2 a1A[kRB], avA[kRB], a1B[kRB], avB[kRB];

  auto loadb = [&](float2 (&a1)[kRB], float2 (&av)[kRB], int t) {
    const float* rp = up + (size_t)t * kRB * kC3;
    #pragma unroll
    for (int k = 0; k < kRB; ++k) {
      a1[k] = *(const float2*)&rp[(size_t)k * kC3 + c1];
      av[k] = *(const float2*)&rp[(size_t)k * kC3 + cv];
    }
  };

  auto comp = [&](const float2 (&a1)[kRB], const float2 (&av)[kRB], int t) {
    #pragma unroll
    for (int k = 0; k < kRB; ++k) {
      const float c1v[2] = {a1[k].x, a1[k].y};
      const float cvv[2] = {av[k].x, av[k].y};
      float xq[2];
      #pragma unroll
      for (int q = 0; q < 2; ++q) {
        const float x1 = fmaf(w1k[q][0], m2_1[q],
                         fmaf(w1k[q][1], m1_1[q],
                         fmaf(w1k[q][2], c1v[q], b1[q])));
        const float v  = fmaf(wvk[q][0], m2_v[q],
                         fmaf(wvk[q][1], m1_v[q],
                         fmaf(wvk[q][2], cvv[q], bv[q])));
        const float x = x1 * v;
        xq[q] = x;
        #pragma unroll
        for (int j = 0; j < kS; ++j) s[q][j] = fmaf(p[q][j], s[q][j], x);
        m2_1[q] = m1_1[q]; m1_1[q] = c1v[q];
        m2_v[q] = m1_v[q]; m1_v[q] = cvv[q];
      }
      *(__half2*)&xb[(size_t)(t * kRB + k) * kHid] =
          __float22half2_rn(make_float2(xq[0], xq[1]));
    }
  };

  loadb(a1A, avA, 0);
  for (int t = 0; t < kNB; t += 2) {
    if (t + 1 < kNB) loadb(a1B, avB, t + 1);
    comp(a1A, avA, t);
    if (t + 2 < kNB) loadb(a1A, avA, t + 2);
    comp(a1B, avB, t + 1);
  }

  float* Ad = A + (((size_t)b * kNC + ch) * kHid + d0) * kS;
  #pragma unroll
  for (int q = 0; q < 2; ++q)
    #pragma unroll
    for (int j = 0; j < kS; ++j) Ad[q * kS + j] = s[q][j];
}

// ---------------------------------------------------------------------------
// Pass 2: in-place inclusive combine across chunks:
//   S[c] = p^CL * S[c-1] + A[c]   (per (b,d,s) line; lines are disjoint)
// ---------------------------------------------------------------------------
__global__ __launch_bounds__(256) void hyena_pass2(
    const float* __restrict__ lp, float* __restrict__ A)
{
  const int t = blockIdx.x * 256 + threadIdx.x;    // over B*HID*S = 32768
  const int j = t & (kS - 1);
  const int d = (t >> 3) & (kHid - 1);
  const int b = t >> 14;
  const float pC = expf(lp[d*kS + j] * (float)kCL);

  const size_t base   = (size_t)b * kNC * kHid * kS + (size_t)d * kS + j;
  const size_t stride = (size_t)kHid * kS;

  float s = 0.f;
  for (int c0 = 0; c0 < kNC; c0 += 8) {
    float a[8];
    #pragma unroll
    for (int k = 0; k < 8; ++k) a[k] = A[base + (size_t)(c0 + k) * stride];
    #pragma unroll
    for (int k = 0; k < 8; ++k) {
      s = fmaf(pC, s, a[k]);
      A[base + (size_t)(c0 + k) * stride] = s;
    }
  }
}

// ---------------------------------------------------------------------------
// Pass 3: read x1v (fp16, from pass 1) and derive x2 from u's x2 columns,
// scan with the combined incoming state (end-state of chunk-1), emit
// out[b][l][d] = (y + x1v*D) * x2.
// ---------------------------------------------------------------------------
__global__ __launch_bounds__(256) void hyena_pass3(
    const float* __restrict__ u, const float* __restrict__ w,
    const float* __restrict__ bias, const float* __restrict__ lp,
    const float* __restrict__ res, const float* __restrict__ Dv,
    const float* __restrict__ A, const __half* __restrict__ xw,
    float* __restrict__ out)
{
  const int tid  = threadIdx.x;
  const int ch   = blockIdx.y;
  const int b    = blockIdx.z;
  const int head = blockIdx.x * 4 + (tid >> 6);
  const int r2   = (tid & 63) * 2;
  const int d0   = head * 128 + r2;
  const int c2   = head * 384 + r2;       // x2 channel

  float w2k[2][3], b2[2], Dd[2];
  #pragma unroll
  for (int q = 0; q < 2; ++q) {
    #pragma unroll
    for (int k = 0; k < 3; ++k) w2k[q][k] = w[(c2 + q) * 3 + k];
    b2[q] = bias[c2 + q];
    Dd[q] = Dv[d0 + q];
  }

  float p[2][kS], rr[2][kS], s[2][kS];
  #pragma unroll
  for (int q = 0; q < 2; ++q)
    #pragma unroll
    for (int j = 0; j < kS; ++j) {
      p[q][j]  = expf(lp[(d0 + q) * kS + j]);
      rr[q][j] = res[(d0 + q) * kS + j];
    }
  if (ch == 0) {
    #pragma unroll
    for (int q = 0; q < 2; ++q)
      #pragma unroll
      for (int j = 0; j < kS; ++j) s[q][j] = 0.f;
  } else {
    const float* Ad = A + (((size_t)b * kNC + (ch - 1)) * kHid + d0) * kS;
    #pragma unroll
    for (int q = 0; q < 2; ++q)
      #pragma unroll
      for (int j = 0; j < kS; ++j) s[q][j] = Ad[q * kS + j];
  }

  const int l0 = ch * kCL;
  const float* ub = u + (size_t)b * kL * kC3;

  float m2_2[2] = {0.f, 0.f}, m1_2[2] = {0.f, 0.f};
  if (l0 >= 2) {
    float2 t2 = *(const float2*)&ub[(size_t)(l0 - 2) * kC3 + c2];
    m2_2[0] = t2.x; m2_2[1] = t2.y;
  }
  if (l0 >= 1) {
    float2 t2 = *(const float2*)&ub[(size_t)(l0 - 1) * kC3 + c2];
    m1_2[0] = t2.x; m1_2[1] = t2.y;
  }

  const float* up = ub + (size_t)l0 * kC3;
  const __half* xb = xw + ((size_t)b * kL + l0) * kHid + d0;
  float* ob = out + ((size_t)b * kL + l0) * kHid + d0;

  float2 a2A[kRB], a2B[kRB];
  __half2 xvA[kRB], xvB[kRB];

  auto loadb = [&](float2 (&a2)[kRB], __half2 (&xv)[kRB], int t) {
    const float* rp = up + (size_t)t * kRB * kC3;
    const __half* xp = xb + (size_t)t * kRB * kHid;
    #pragma unroll
    for (int k = 0; k < kRB; ++k) {
      a2[k] = *(const float2*)&rp[(size_t)k * kC3 + c2];
      xv[k] = *(const __half2*)&xp[(size_t)k * kHid];
    }
  };

  auto comp = [&](const float2 (&a2)[kRB], const __half2 (&xv)[kRB], int t) {
    #pragma unroll
    for (int k = 0; k < kRB; ++k) {
      const float c2v[2] = {a2[k].x, a2[k].y};
      const float2 xf = __half22float2(xv[k]);
      const float xq[2] = {xf.x, xf.y};
      float o[2];
      #pragma unroll
      for (int q = 0; q < 2; ++q) {
        const float x2 = fmaf(w2k[q][0], m2_2[q],
                         fmaf(w2k[q][1], m1_2[q],
                         fmaf(w2k[q][2], c2v[q], b2[q])));
        const float x = xq[q];
        #pragma unroll
        for (int j = 0; j < kS; ++j) s[q][j] = fmaf(p[q][j], s[q][j], x);
        float y = 0.f;
        #pragma unroll
        for (int j = 0; j < kS; ++j) y = fmaf(rr[q][j], s[q][j], y);
        o[q] = fmaf(x, Dd[q], y) * x2;
        m2_2[q] = m1_2[q]; m1_2[q] = c2v[q];
      }
      *(float2*)&ob[(size_t)(t * kRB + k) * kHid] = make_float2(o[0], o[1]);
    }
  };

  loadb(a2A, xvA, 0);
  for (int t = 0; t < kNB; t += 2) {
    if (t + 1 < kNB) loadb(a2B, xvB, t + 1);
    comp(a2A, xvA, t);
    if (t + 2 < kNB) loadb(a2A, xvA, t + 2);
    comp(a2B, xvB, t + 1);
  }
}

extern "C" void kernel_launch(void* const* d_in, const int* in_sizes, int n_in,
                              void* d_out, int out_size, void* d_ws, size_t ws_size,
                              hipStream_t stream) {
  const float* u    = (const float*)d_in[0];  // [B, L, 3*HID] fp32
  const float* w    = (const float*)d_in[1];  // [3*HID, 1, 3]
  const float* bias = (const float*)d_in[2];  // [3*HID]
  const float* lp   = (const float*)d_in[3];  // [HID, S, 1]
  const float* res  = (const float*)d_in[4];  // [HID, S]
  const float* Dv   = (const float*)d_in[5];  // [HID]
  float* out = (float*)d_out;                 // [B, L, HID]
  float* A   = (float*)d_ws;                  // [B, NC, HID, S] = 8 MB
  __half* xw = (__half*)((char*)d_ws + (size_t)kB * kNC * kHid * kS * 4);
                                              // x1v fp16 [B, L, HID] = 67 MB

  const dim3 blk(256);
  const dim3 g13(kHid / 512, kNC, kB);        // (head-quads, chunks, batch)
  hipLaunchKernelGGL(hyena_pass1, g13, blk, 0, stream, u, w, bias, lp, A, xw);
  hipLaunchKernelGGL(hyena_pass2, dim3((kB * kHid * kS) / 256), blk, 0, stream, lp, A);
  hipLaunchKernelGGL(hyena_pass3, g13, blk, 0, stream, u, w, bias, lp, res, Dv, A, xw, out);
}